// Round 3
// baseline (309.963 us; speedup 1.0000x reference)
//
#include <hip/hip_runtime.h>
#include <stdint.h>

// RGCNConv: out = sum_r ((A * [edge==r]) @ x) @ W_r + bias
// N=4096, IN=OUT=256, R=8.
//   k_init : out[i][o] = bias[o]
//   k_y    : y_t[o][j*8+r] = (x @ W_r)[j][o]  (bf16, in ws, 16 MB)
//   k_main : expanded GEMM out[i][o] += sum_j A[i][j] * y_t[o][j*8+e[i][j]]
//            A/et read as FULL 128B lines into registers (j-group 32,
//            consumed over 4 sub-steps of 8 j); B via global_load_lds dbuf
//            (16KB buffers). One-hot A frags built in registers.

#define NN 4096

typedef __attribute__((ext_vector_type(8))) short  s16x8;   // 8 bf16 MFMA frag
typedef __attribute__((ext_vector_type(4))) float  fx4;
typedef __attribute__((ext_vector_type(4))) int    ix4;
typedef __attribute__((ext_vector_type(4))) unsigned int ux4;

union uq { ux4 u; s16x8 s; };

__device__ __forceinline__ unsigned short f2bf(float f) {
  union { float f; unsigned int u; } v; v.f = f;
  unsigned int r = v.u + 0x7fffu + ((v.u >> 16) & 1u);  // RNE
  return (unsigned short)(r >> 16);
}

__device__ __forceinline__ void gld16(const void* g, void* l) {
  __builtin_amdgcn_global_load_lds(
      (const __attribute__((address_space(1))) unsigned int*)(uintptr_t)g,
      (__attribute__((address_space(3))) unsigned int*)(uintptr_t)l, 16, 0, 0);
}

// ---------------- init: out = bias ----------------
__global__ void k_init(const float* __restrict__ bias, float* __restrict__ out) {
  int idx = blockIdx.x * 256 + threadIdx.x;
  out[idx] = bias[idx & 255];
}

// ---------------- y_t[o][j*8+r] = sum_k x[j][k] * W[r][k][o] ----------------
__global__ __launch_bounds__(256) void k_y(const float* __restrict__ x,
                                           const float* __restrict__ W,
                                           unsigned short* __restrict__ yt) {
  __shared__ unsigned short Wl[128 * 256];  // 64 KB
  const int t  = threadIdx.x;
  const int j0 = blockIdx.x * 64;
  const int o0 = blockIdx.y * 16;

  {
    const int r = t >> 5, kc = t & 31;
#pragma unroll
    for (int u = 0; u < 8; ++u) {
      const int k = kc * 8 + u;
      const fx4* wp = (const fx4*)(W + ((size_t)r * 256 + k) * 256 + o0);
      fx4 w[4] = { wp[0], wp[1], wp[2], wp[3] };
#pragma unroll
      for (int i = 0; i < 16; ++i) {
        const int row = i * 8 + r;               // n'
        const int gs  = (k >> 3) ^ (row & 7);    // swizzled 16B granule
        Wl[row * 256 + gs * 8 + (k & 7)] = f2bf(w[i >> 2][i & 3]);
      }
    }
  }
  __syncthreads();

  const int lane = t & 63, wid = t >> 6;
  const int l15 = lane & 15, lh = lane >> 4;
  const int npb = wid * 32;

  fx4 acc[4][2];
#pragma unroll
  for (int m = 0; m < 4; ++m)
#pragma unroll
    for (int n = 0; n < 2; ++n) acc[m][n] = 0.f;

  unsigned int qb[2];
#pragma unroll
  for (int n = 0; n < 2; ++n) {
    int row = npb + n * 16 + l15;
    qb[n] = (unsigned)(row * 512 + 16 * (lh ^ (row & 3))) ^ (64u * ((row >> 2) & 1));
  }
  const char* WlB = (const char*)Wl;
  const float* xb = x + (size_t)(j0 + l15) * 256 + lh * 8;

#pragma unroll
  for (int ks = 0; ks < 8; ++ks) {
    s16x8 a[4];
#pragma unroll
    for (int m = 0; m < 4; ++m) {
      const fx4* xp = (const fx4*)(xb + (size_t)m * 16 * 256 + ks * 32);
      fx4 x0 = xp[0], x1 = xp[1];
      s16x8 av;
#pragma unroll
      for (int i = 0; i < 4; ++i) av[i] = (short)f2bf(x0[i]);
#pragma unroll
      for (int i = 0; i < 4; ++i) av[4 + i] = (short)f2bf(x1[i]);
      a[m] = av;
    }
#pragma unroll
    for (int n = 0; n < 2; ++n) {
      s16x8 b = *(const s16x8*)(WlB + (qb[n] ^ (unsigned)(ks * 64)));
#pragma unroll
      for (int m = 0; m < 4; ++m)
        acc[m][n] = __builtin_amdgcn_mfma_f32_16x16x32_bf16(a[m], b, acc[m][n], 0, 0, 0);
    }
  }

#pragma unroll
  for (int m = 0; m < 4; ++m)
#pragma unroll
    for (int n = 0; n < 2; ++n)
#pragma unroll
      for (int q = 0; q < 4; ++q) {
        int jl = m * 16 + lh * 4 + q;
        int np = npb + n * 16 + l15;
        int o  = o0 + (np >> 3);
        yt[(size_t)o * 32768 + (size_t)(j0 + jl) * 8 + (np & 7)] = f2bf(acc[m][n][q]);
      }
}

// ---------------- main expanded GEMM ----------------
// grid (16 mtiles, 2 ntiles, 16 ksplit), 256 thr (4 waves, wave-tile 64x128
// m-split -> block 256 x 128). j-window 256 = 8 groups x 32 j; each group =
// 4 sub-steps (h) of 8 j (K_eff 64, 2 MFMA k-slices).
// j mapping: j_local = lh*8 + 2h + ks  (bijection over (h,ks,lh)).
// A/et: per m one fx4 pair at j = lh*8..+7 (full 128B line per row, one
// coalesced instr); component c = 2h+ks; lo half reloaded after h=1, hi
// after h=3 (next group, ~2 sub-steps ahead).
// B: LDS dbuf 2 x (128 rows x 8 slots x 16B) = 32 KB via global_load_lds;
// physical slot sp = sl ^ (row&7); read at sl = lh*2+ks.
__global__ __launch_bounds__(256, 2) void k_main(const float* __restrict__ A,
                                                 const int*   __restrict__ et,
                                                 const unsigned short* __restrict__ yt,
                                                 float* __restrict__ out) {
  __shared__ ux4 Bl[2 * 1024];  // 32 KB
  const int t = threadIdx.x, lane = t & 63, wid = t >> 6;
  const int l15 = lane & 15, lh = lane >> 4;
  const int i0 = blockIdx.x * 256;
  const int o0 = blockIdx.y * 128;
  const int jb = blockIdx.z * 256;

  const ux4* ytg = (const ux4*)yt;  // [o][4096] 16B granules

  // A/et lane bases: row i = i0 + wid*64 + m*16 + l15, col jb + lh*8
  const float* pA[4]; const int* pE[4];
#pragma unroll
  for (int m = 0; m < 4; ++m) {
    size_t off = (size_t)(i0 + wid * 64 + m * 16 + l15) * NN + jb + lh * 8;
    pA[m] = A + off; pE[m] = et + off;
  }

  // staging: per wave 4KB (32 rows x 8 slots); lane -> (row group, phys slot)
  const int srl = lane >> 3;          // row within 8-row group
  const int sp  = lane & 7;           // physical slot
#define STAGE(gg, hh, bb) do {                                           \
    _Pragma("unroll")                                                    \
    for (int u = 0; u < 4; ++u) {                                        \
      int row = wid * 32 + u * 8 + srl;                                  \
      int sl  = sp ^ (row & 7);                                          \
      int jg  = jb + (gg) * 32 + (sl >> 1) * 8 + (hh) * 2 + (sl & 1);    \
      gld16(ytg + ((size_t)(o0 + row) << 12) + jg,                       \
            Bl + (bb) * 1024 + (wid * 32 + u * 8) * 8);                  \
    }                                                                    \
  } while (0)

  // group-0 A/et registers
  fx4 rAlo[4], rAhi[4]; ix4 rElo[4], rEhi[4];
#pragma unroll
  for (int m = 0; m < 4; ++m) {
    rAlo[m] = *(const fx4*)(pA[m]);     rAhi[m] = *(const fx4*)(pA[m] + 4);
    rElo[m] = *(const ix4*)(pE[m]);     rEhi[m] = *(const ix4*)(pE[m] + 4);
  }
  STAGE(0, 0, 0);
  __syncthreads();

  fx4 acc[4][8];
#pragma unroll
  for (int m = 0; m < 4; ++m)
#pragma unroll
    for (int n = 0; n < 8; ++n) acc[m][n] = 0.f;

  const char* ldsc = (const char*)Bl;

  for (int g = 0; g < 8; ++g) {
    const int gn = (g < 7) ? g + 1 : 7;
#pragma unroll
    for (int h = 0; h < 4; ++h) {
      const int s = g * 4 + h;
      if (s < 31) {                       // stage next sub-step (uniform)
        const int hN = (h + 1) & 3;
        const int gN = (h == 3) ? g + 1 : g;
        STAGE(gN, hN, (s + 1) & 1);
      }
      const unsigned bufoff = (unsigned)(s & 1) * 16384u;
#pragma unroll
      for (int ks = 0; ks < 2; ++ks) {
        const int c = h * 2 + ks;         // static after unroll
        uq a4[4];
#pragma unroll
        for (int m = 0; m < 4; ++m) {
          float av = (c < 4) ? rAlo[m][c] : rAhi[m][c - 4];
          int   ev = (c < 4) ? rElo[m][c] : rEhi[m][c - 4];
          unsigned long long sh = ((unsigned long long)f2bf(av)) << ((ev & 3) * 16);
          unsigned lo = (unsigned)sh, hi = (unsigned)(sh >> 32);
          bool cc = ev < 4;
          ux4 q;
          q.x = cc ? lo : 0u; q.y = cc ? hi : 0u; q.z = cc ? 0u : lo; q.w = cc ? 0u : hi;
          a4[m].u = q;
        }
#pragma unroll
        for (int n = 0; n < 8; ++n) {
          int row = n * 16 + l15;
          unsigned off = bufoff + (unsigned)(row * 128)
                       + (unsigned)((((lh * 2 + ks) ^ (row & 7)) * 16));
          uq b; b.u = *(const ux4*)(ldsc + off);
#pragma unroll
          for (int m = 0; m < 4; ++m)
            acc[m][n] = __builtin_amdgcn_mfma_f32_16x16x32_bf16(a4[m].s, b.s, acc[m][n], 0, 0, 0);
        }
      }
      if (h == 1) {                       // reload lo half for next group
#pragma unroll
        for (int m = 0; m < 4; ++m) {
          rAlo[m] = *(const fx4*)(pA[m] + gn * 32);
          rElo[m] = *(const ix4*)(pE[m] + gn * 32);
        }
      }
      if (h == 3) {                       // reload hi half for next group
#pragma unroll
        for (int m = 0; m < 4; ++m) {
          rAhi[m] = *(const fx4*)(pA[m] + gn * 32 + 4);
          rEhi[m] = *(const ix4*)(pE[m] + gn * 32 + 4);
        }
      }
      __syncthreads();
    }
  }

  // epilogue: K-split partial accumulate
#pragma unroll
  for (int m = 0; m < 4; ++m)
#pragma unroll
    for (int n = 0; n < 8; ++n)
#pragma unroll
      for (int q = 0; q < 4; ++q) {
        int gi = i0 + wid * 64 + m * 16 + lh * 4 + q;
        int go = o0 + n * 16 + l15;
        atomicAdd(out + (size_t)gi * 256 + go, acc[m][n][q]);
      }
#undef STAGE
}

extern "C" void kernel_launch(void* const* d_in, const int* in_sizes, int n_in,
                              void* d_out, int out_size, void* d_ws, size_t ws_size,
                              hipStream_t stream) {
  const float* x    = (const float*)d_in[0];
  const float* A    = (const float*)d_in[1];
  const int*   et   = (const int*)d_in[2];
  const float* W    = (const float*)d_in[3];
  const float* bias = (const float*)d_in[4];
  float* out = (float*)d_out;
  unsigned short* yt = (unsigned short*)d_ws;  // 16 MB

  k_init<<<dim3(4096), dim3(256), 0, stream>>>(bias, out);
  k_y   <<<dim3(64, 16), dim3(256), 0, stream>>>(x, W, yt);
  k_main<<<dim3(16, 2, 16), dim3(256), 0, stream>>>(A, et, yt, out);
}

// Round 4
// 144.496 us; speedup vs baseline: 2.1451x; 2.1451x over previous
//
#include <hip/hip_runtime.h>
#include <stdint.h>

// RGCNConv: out = sum_r ((A * [edge==r]) @ x) @ W_r + bias
// N=4096, IN=OUT=256, R=8.
//   k_init : out[i][o] = bias[o]
//   k_y    : y_t[o][j*8+r] = (x @ W_r)[j][o]  (bf16, in ws, 16 MB)
//   k_main : expanded GEMM out[i][o] += sum_j A[i][j] * y_t[o][j*8+e[i][j]]
//            ALL streams staged via global_load_lds into a 3-deep circular
//            LDS pipeline; counted s_waitcnt vmcnt(6) + raw s_barrier per
//            step (loads stay in flight across barriers). A one-hot frags
//            built in registers from LDS read-back. Round-1 memory shape
//            (128-row blocks) which measured compulsory FETCH.

#define NN 4096

typedef __attribute__((ext_vector_type(8))) short  s16x8;   // 8 bf16 MFMA frag
typedef __attribute__((ext_vector_type(4))) float  fx4;
typedef __attribute__((ext_vector_type(4))) unsigned int ux4;

union uq { ux4 u; s16x8 s; };

__device__ __forceinline__ unsigned short f2bf(float f) {
  union { float f; unsigned int u; } v; v.f = f;
  unsigned int r = v.u + 0x7fffu + ((v.u >> 16) & 1u);  // RNE
  return (unsigned short)(r >> 16);
}

__device__ __forceinline__ void gld16(const void* g, void* l) {
  __builtin_amdgcn_global_load_lds(
      (const __attribute__((address_space(1))) unsigned int*)(uintptr_t)g,
      (__attribute__((address_space(3))) unsigned int*)(uintptr_t)l, 16, 0, 0);
}

// ---------------- init: out = bias ----------------
__global__ void k_init(const float* __restrict__ bias, float* __restrict__ out) {
  int idx = blockIdx.x * 256 + threadIdx.x;
  out[idx] = bias[idx & 255];
}

// ---------------- y_t[o][j*8+r] = sum_k x[j][k] * W[r][k][o] ----------------
// grid (32 jtiles, 16 otiles), 256 thr. Block: j 128 x n' 128 (n'=(o-o0)*8+r).
__global__ __launch_bounds__(256, 2) void k_y(const float* __restrict__ x,
                                              const float* __restrict__ W,
                                              unsigned short* __restrict__ yt) {
  __shared__ unsigned short Wl[128 * 256];  // 64 KB
  const int t  = threadIdx.x;
  const int j0 = blockIdx.x * 128;
  const int o0 = blockIdx.y * 16;

  {
    const int r = t >> 5, kc = t & 31;
#pragma unroll
    for (int u = 0; u < 8; ++u) {
      const int k = kc * 8 + u;
      const fx4* wp = (const fx4*)(W + ((size_t)r * 256 + k) * 256 + o0);
      fx4 w[4] = { wp[0], wp[1], wp[2], wp[3] };
#pragma unroll
      for (int i = 0; i < 16; ++i) {
        const int row = i * 8 + r;               // n'
        const int gs  = (k >> 3) ^ (row & 7);    // swizzled 16B granule
        Wl[row * 256 + gs * 8 + (k & 7)] = f2bf(w[i >> 2][i & 3]);
      }
    }
  }
  __syncthreads();

  const int lane = t & 63, wid = t >> 6;
  const int l15 = lane & 15, lh = lane >> 4;
  const int npb = wid * 32;

  fx4 acc[8][2];
#pragma unroll
  for (int m = 0; m < 8; ++m)
#pragma unroll
    for (int n = 0; n < 2; ++n) acc[m][n] = 0.f;

  unsigned int qb[2];
#pragma unroll
  for (int n = 0; n < 2; ++n) {
    int row = npb + n * 16 + l15;
    qb[n] = (unsigned)(row * 512 + 16 * (lh ^ (row & 3))) ^ (64u * ((row >> 2) & 1));
  }
  const char* WlB = (const char*)Wl;
  const float* xb = x + (size_t)(j0 + l15) * 256 + lh * 8;

#pragma unroll
  for (int ks = 0; ks < 8; ++ks) {
    s16x8 a[8];
#pragma unroll
    for (int m = 0; m < 8; ++m) {
      const fx4* xp = (const fx4*)(xb + (size_t)m * 16 * 256 + ks * 32);
      fx4 x0 = xp[0], x1 = xp[1];
      s16x8 av;
#pragma unroll
      for (int i = 0; i < 4; ++i) av[i] = (short)f2bf(x0[i]);
#pragma unroll
      for (int i = 0; i < 4; ++i) av[4 + i] = (short)f2bf(x1[i]);
      a[m] = av;
    }
#pragma unroll
    for (int n = 0; n < 2; ++n) {
      s16x8 b = *(const s16x8*)(WlB + (qb[n] ^ (unsigned)(ks * 64)));
#pragma unroll
      for (int m = 0; m < 8; ++m)
        acc[m][n] = __builtin_amdgcn_mfma_f32_16x16x32_bf16(a[m], b, acc[m][n], 0, 0, 0);
    }
  }

#pragma unroll
  for (int m = 0; m < 8; ++m)
#pragma unroll
    for (int n = 0; n < 2; ++n)
#pragma unroll
      for (int q = 0; q < 4; ++q) {
        int jl = m * 16 + lh * 4 + q;
        int np = npb + n * 16 + l15;
        int o  = o0 + (np >> 3);
        yt[(size_t)o * 32768 + (size_t)(j0 + jl) * 8 + (np & 7)] = f2bf(acc[m][n][q]);
      }
}

// ---------------- main expanded GEMM ----------------
// grid (32 mtiles, 2 ntiles, 8 ksplit) = 512 blocks (2/CU). Block 128x128,
// 4 waves (wave tile 64x64). j-window 512 = 64 steps x 8 j (K_eff 64/step).
// j mapping within step: j = ks*4 + lh.
// LDS 72 KB, 3-deep circular: A raw [3][128 i][8 j] f32 @0, E same @12288,
// B [3][128 o][8 slots x 16B granules] @24576 (slot sp = sl ^ (row&7)).
// Per step/thread: 6 gld16. Steady state: s_waitcnt vmcnt(6) (stage s done,
// stage s+1 in flight) -> s_barrier -> issue stage s+2 -> compute s.
__global__ __launch_bounds__(256, 2) void k_main(const float* __restrict__ A,
                                                 const int*   __restrict__ et,
                                                 const unsigned short* __restrict__ yt,
                                                 float* __restrict__ out) {
  __shared__ ux4 smem[4608];  // 73728 B
  const int t = threadIdx.x, lane = t & 63, w = t >> 6;
  const int l15 = lane & 15, lh = lane >> 4;
  const int wm = w >> 1, wn = w & 1;
  const int i0 = blockIdx.x * 128;
  const int o0 = blockIdx.y * 128;
  const int jb = blockIdx.z * 512;

  float* Af = (float*)smem;                    // 3 x 1024 words
  int*   Ef = (int*)((char*)smem + 12288);
  char*  Bc = (char*)smem + 24576;
  char*  smc = (char*)smem;

  // staging sources (step stride: 8 floats / 8 granules)
  const float* sA = A  + (size_t)(i0 + (t >> 1)) * NN + jb + (t & 1) * 4;
  const int*   sE = et + (size_t)(i0 + (t >> 1)) * NN + jb + (t & 1) * 4;
  const ux4* ytg = (const ux4*)yt;             // [o][4096] granules
  const ux4* sB[4];
#pragma unroll
  for (int u = 0; u < 4; ++u) {
    int row = w * 32 + u * 8 + (lane >> 3);
    int sl  = (lane & 7) ^ (row & 7);
    sB[u] = ytg + ((size_t)(o0 + row) << 12) + jb + sl;
  }

#define STAGE(sq, p) do {                                                 \
    gld16(sA + (size_t)(sq) * 8, smc + (p) * 4096 + w * 1024);            \
    gld16(sE + (size_t)(sq) * 8, smc + 12288 + (p) * 4096 + w * 1024);    \
    _Pragma("unroll")                                                     \
    for (int u = 0; u < 4; ++u)                                           \
      gld16(sB[u] + (size_t)(sq) * 8,                                     \
            Bc + (p) * 16384 + (w * 32 + u * 8) * 128);                   \
  } while (0)

  // loop-invariant read indices
  int ibase[4];
#pragma unroll
  for (int m = 0; m < 4; ++m)
    ibase[m] = (wm * 64 + m * 16 + l15) * 8 + lh;   // word idx in A/E buf
  unsigned Qb[4];
#pragma unroll
  for (int n = 0; n < 4; ++n) {
    int row = wn * 64 + n * 16 + l15;
    Qb[n] = (unsigned)(row * 128 + ((lh ^ (row & 7)) << 4));
  }

  fx4 acc[4][4];
#pragma unroll
  for (int m = 0; m < 4; ++m)
#pragma unroll
    for (int n = 0; n < 4; ++n) acc[m][n] = 0.f;

  // prologue: 2 stages in flight
  STAGE(0, 0);
  STAGE(1, 1);

  int p = 0;
  for (int s = 0; s < 64; ++s) {
    asm volatile("s_waitcnt vmcnt(6)" ::: "memory");  // stage(s) landed
    __builtin_amdgcn_s_barrier();                     // all waves' stage(s) visible
    {
      int sq = (s + 2 > 63) ? 63 : s + 2;
      int p2 = p + 2; if (p2 >= 3) p2 -= 3;
      STAGE(sq, p2);                                  // overwrites buf read in step s-1
    }
    const int pW = p * 1024;
    const unsigned pB = (unsigned)(p * 16384);
    float aLo[4], aHi[4]; int eLo[4], eHi[4];
#pragma unroll
    for (int m = 0; m < 4; ++m) {
      int idx = pW + ibase[m];
      aLo[m] = Af[idx]; aHi[m] = Af[idx + 4];
      eLo[m] = Ef[idx]; eHi[m] = Ef[idx + 4];
    }
#pragma unroll
    for (int ks = 0; ks < 2; ++ks) {
      uq a4[4];
#pragma unroll
      for (int m = 0; m < 4; ++m) {
        float av = ks ? aHi[m] : aLo[m];
        int   ev = ks ? eHi[m] : eLo[m];
        unsigned long long sh = ((unsigned long long)f2bf(av)) << ((ev & 3) * 16);
        unsigned lo = (unsigned)sh, hi = (unsigned)(sh >> 32);
        bool c = ev < 4;
        ux4 q;
        q.x = c ? lo : 0u; q.y = c ? hi : 0u; q.z = c ? 0u : lo; q.w = c ? 0u : hi;
        a4[m].u = q;
      }
#pragma unroll
      for (int n = 0; n < 4; ++n) {
        uq b; b.u = *(const ux4*)(Bc + pB + (Qb[n] ^ (unsigned)(ks * 64)));
#pragma unroll
        for (int m = 0; m < 4; ++m)
          acc[m][n] = __builtin_amdgcn_mfma_f32_16x16x32_bf16(a4[m].s, b.s, acc[m][n], 0, 0, 0);
      }
    }
    p = (p == 2) ? 0 : p + 1;
  }
  asm volatile("s_waitcnt vmcnt(0)" ::: "memory");  // drain DMA before LDS dealloc

  // epilogue: K-split partial accumulate
#pragma unroll
  for (int m = 0; m < 4; ++m)
#pragma unroll
    for (int n = 0; n < 4; ++n)
#pragma unroll
      for (int q = 0; q < 4; ++q) {
        int gi = i0 + wm * 64 + m * 16 + lh * 4 + q;
        int go = o0 + wn * 64 + n * 16 + l15;
        atomicAdd(out + (size_t)gi * 256 + go, acc[m][n][q]);
      }
#undef STAGE
}

extern "C" void kernel_launch(void* const* d_in, const int* in_sizes, int n_in,
                              void* d_out, int out_size, void* d_ws, size_t ws_size,
                              hipStream_t stream) {
  const float* x    = (const float*)d_in[0];
  const float* A    = (const float*)d_in[1];
  const int*   et   = (const int*)d_in[2];
  const float* W    = (const float*)d_in[3];
  const float* bias = (const float*)d_in[4];
  float* out = (float*)d_out;
  unsigned short* yt = (unsigned short*)d_ws;  // 16 MB

  k_init<<<dim3(4096), dim3(256), 0, stream>>>(bias, out);
  k_y   <<<dim3(32, 16), dim3(256), 0, stream>>>(x, W, yt);
  k_main<<<dim3(32, 2, 8), dim3(256), 0, stream>>>(A, et, yt, out);
}